// Round 11
// baseline (507.669 us; speedup 1.0000x reference)
//
#include <hip/hip_runtime.h>
#include <cstddef>

#define EMBED   768
#define NHEADS  12
#define HDIM    64
#define KSZ     7
#define IMG_H   64
#define IMG_W   64
#define BATCH   8
#define NTOK    (BATCH*IMG_H*IMG_W)   /* 32768 */
#define QKV_N   (3*EMBED)             /* 2304  */

typedef __attribute__((ext_vector_type(8))) short  bf16x8;
typedef __attribute__((ext_vector_type(4))) float  f32x4;
typedef __attribute__((ext_vector_type(8))) unsigned short u16x8;
typedef __attribute__((ext_vector_type(4))) unsigned short u16x4;

__device__ __forceinline__ unsigned short f2bf(float f) {
    unsigned int u = __float_as_uint(f);
    u += 0x7FFFu + ((u >> 16) & 1u);      // RNE
    return (unsigned short)(u >> 16);
}

__device__ __forceinline__ void gload_lds16(const void* g, void* l) {
    __builtin_amdgcn_global_load_lds(
        (const __attribute__((address_space(1))) unsigned int*)g,
        (__attribute__((address_space(3))) unsigned int*)l, 16, 0, 0);
}

// ---------------- fused fp32 -> bf16 conversion (x, w_qkv, w_proj in one launch) ----
__global__ __launch_bounds__(256)
void cvt_all_kernel(const float* __restrict__ x, const float* __restrict__ wq,
                    const float* __restrict__ wp, unsigned short* __restrict__ xbf,
                    unsigned short* __restrict__ wqbf, unsigned short* __restrict__ wpbf)
{
    const int NX = NTOK * EMBED / 4;
    const int NQ = QKV_N * EMBED / 4;
    const int NP = EMBED * EMBED / 4;
    int i = blockIdx.x * 256 + threadIdx.x;
    const float* src; unsigned short* dst; int j;
    if (i < NX)           { src = x;  dst = xbf;  j = i; }
    else if (i < NX + NQ) { src = wq; dst = wqbf; j = i - NX; }
    else if (i < NX + NQ + NP) { src = wp; dst = wpbf; j = i - NX - NQ; }
    else return;
    float4 f = *(const float4*)(src + (size_t)j * 4);
    u16x4 o;
    o[0] = f2bf(f.x); o[1] = f2bf(f.y); o[2] = f2bf(f.z); o[3] = f2bf(f.w);
    *(u16x4*)(dst + (size_t)j * 4) = o;
}

// ---------------- bf16 MFMA GEMM v8: v7 K-loop (proven) + dense LDS-bounce epilogue ----
// K-loop identical to round 9/10 (256x256, BK=64, 8 waves, 2x64KB LDS, 4-phase counted
// vmcnt(4), fragment-linear slot-permuted LDS, 0 bank conflicts, race-free).
// v8 epilogue: per-wave LDS bounce with DENSE line coverage. Round-7's 5x write
// amplification came from each store instruction half-covering 128B lines (RMW at TCC).
// Now: bf16 -> wave tile 16x64 is a contiguous 2KB LDS region; store insn lane map
// (row=l>>3, col=(l&7)*8) covers each 128B row-line fully in ONE instruction. fp32 ->
// 4 stores, lanes 0-15 cover one 256B row densely. LDS reads are pure stride-1 (free).
template<int BF16OUT>
__global__ __launch_bounds__(512)
void gemm256(const unsigned short* __restrict__ A, const unsigned short* __restrict__ W,
             const float* __restrict__ bias, void* __restrict__ outp,
             int M, int N, int K, int scaleN, float scale)
{
    __shared__ unsigned short lds[65536];   // 128 KiB: buf c at c (ushorts), B at +16384
    const int t_ = threadIdx.x;
    const int l = t_ & 63, w = t_ >> 6;
    const int wm = w >> 2, wn = w & 3;

    // bn-fastest serpentine mapping within XCD (round-10 proven: FETCH 229->100 MB)
    const int nby = N >> 8;
    const int xcd = blockIdx.x & 7;
    const int loc = blockIdx.x >> 3;
    const int bmg = loc / nby;
    int bnq = loc - bmg * nby;
    if (bmg & 1) bnq = nby - 1 - bnq;
    const int bm = (xcd * (((M >> 8) >> 3)) + bmg) << 8;
    const int bn = bnq << 8;

    // staging source (quad-coalesced, slot-permuted)
    const int kperm8 = ((l & 3) ^ ((l >> 3) & 3)) * 8;
    const unsigned short* gA = A + (size_t)(bm + 2 * w * 16 + (l >> 2)) * K + kperm8;
    const unsigned short* gB = W + (size_t)(bn + 2 * w * 16 + (l >> 2)) * K + kperm8;
    const size_t rstep = (size_t)16 * K;

    const int dA = w * 2048;
    const int foff = (l & 15) * 32 + (((l >> 4) ^ ((l >> 1) & 3)) * 8);
    const int aoff = wm * 8192;
    const int boff = 16384 + wn * 4096;

    f32x4 acc[8][4] = {};
    const int NT = K / 64;

#define BARRIER() asm volatile("s_barrier" ::: "memory")
#define WAITV4()  asm volatile("s_waitcnt vmcnt(4)" ::: "memory")
#define WAITV0()  asm volatile("s_waitcnt vmcnt(0)" ::: "memory")
#define STGA(c, k0, kk) do { \
        gload_lds16(gA + (size_t)(k0) + (kk) * 32,         lds + (c) + dA + (kk) * 512); \
        gload_lds16(gA + rstep + (size_t)(k0) + (kk) * 32, lds + (c) + dA + (2 + (kk)) * 512); } while (0)
#define STGB(c, k0, kk) do { \
        gload_lds16(gB + (size_t)(k0) + (kk) * 32,         lds + (c) + 16384 + dA + (kk) * 512); \
        gload_lds16(gB + rstep + (size_t)(k0) + (kk) * 32, lds + (c) + 16384 + dA + (2 + (kk)) * 512); } while (0)

    // prologue: stage tile 0 in FIFO order A0,B0,A1,B1; retire kh0
    STGA(0, 0, 0); STGB(0, 0, 0); STGA(0, 0, 1); STGB(0, 0, 1);
    WAITV4();
    BARRIER();

    for (int t = 0; t < NT; ++t) {
        const int c  = (t & 1) << 15;
        const int cn = c ^ 32768;
        const int k1 = (t + 1) * 64;
        const bool pf = (t + 1) < NT;

        bf16x8 a[4], bq[4];

        // ---- phase 0: kk0, m0-3 ----
        #pragma unroll
        for (int m = 0; m < 4; ++m) a[m]  = *(const bf16x8*)(lds + c + aoff + (m * 2) * 512 + foff);
        #pragma unroll
        for (int n = 0; n < 4; ++n) bq[n] = *(const bf16x8*)(lds + c + boff + (n * 2) * 512 + foff);
        if (pf) STGA(cn, k1, 0);
        BARRIER();
        __builtin_amdgcn_s_setprio(1);
        #pragma unroll
        for (int m = 0; m < 4; ++m)
            #pragma unroll
            for (int n = 0; n < 4; ++n)
                acc[m][n] = __builtin_amdgcn_mfma_f32_16x16x32_bf16(a[m], bq[n], acc[m][n], 0, 0, 0);
        __builtin_amdgcn_s_setprio(0);

        // ---- phase 1: kk0, m4-7 ----
        #pragma unroll
        for (int m = 0; m < 4; ++m) a[m] = *(const bf16x8*)(lds + c + aoff + ((4 + m) * 2) * 512 + foff);
        if (pf) { STGB(cn, k1, 0); WAITV4(); } else { WAITV0(); }
        BARRIER();
        __builtin_amdgcn_s_setprio(1);
        #pragma unroll
        for (int m = 0; m < 4; ++m)
            #pragma unroll
            for (int n = 0; n < 4; ++n)
                acc[4 + m][n] = __builtin_amdgcn_mfma_f32_16x16x32_bf16(a[m], bq[n], acc[4 + m][n], 0, 0, 0);
        __builtin_amdgcn_s_setprio(0);

        // ---- phase 2: kk1, m0-3 ----
        #pragma unroll
        for (int m = 0; m < 4; ++m) a[m]  = *(const bf16x8*)(lds + c + aoff + (m * 2 + 1) * 512 + foff);
        #pragma unroll
        for (int n = 0; n < 4; ++n) bq[n] = *(const bf16x8*)(lds + c + boff + (n * 2 + 1) * 512 + foff);
        if (pf) STGA(cn, k1, 1);
        BARRIER();
        __builtin_amdgcn_s_setprio(1);
        #pragma unroll
        for (int m = 0; m < 4; ++m)
            #pragma unroll
            for (int n = 0; n < 4; ++n)
                acc[m][n] = __builtin_amdgcn_mfma_f32_16x16x32_bf16(a[m], bq[n], acc[m][n], 0, 0, 0);
        __builtin_amdgcn_s_setprio(0);

        // ---- phase 3: kk1, m4-7 ----
        #pragma unroll
        for (int m = 0; m < 4; ++m) a[m] = *(const bf16x8*)(lds + c + aoff + ((4 + m) * 2 + 1) * 512 + foff);
        if (pf) { STGB(cn, k1, 1); WAITV4(); }
        BARRIER();
        __builtin_amdgcn_s_setprio(1);
        #pragma unroll
        for (int m = 0; m < 4; ++m)
            #pragma unroll
            for (int n = 0; n < 4; ++n)
                acc[4 + m][n] = __builtin_amdgcn_mfma_f32_16x16x32_bf16(a[m], bq[n], acc[4 + m][n], 0, 0, 0);
        __builtin_amdgcn_s_setprio(0);
    }
#undef BARRIER
#undef WAITV4
#undef WAITV0
#undef STGA
#undef STGB

    // ---- epilogue: per-wave LDS bounce, dense line-covering stores ----
    // Safe without an extra barrier: every wave has passed the final phase-3 barrier
    // (all LDS reads precede it); epilogue writes land in buffer-0 bytes [w*4K, +4K),
    // last read at tile NT-2. vmcnt is 0 (phase-1 WAITV0 on the last tile).
    const int cr = (l >> 4) * 4;
    const int cc = l & 15;
    const int colbase = bn + wn * 64;

    if (BF16OUT) {
        unsigned short* eb = lds + w * 2048;            // 2 KiB used per wave
        unsigned short* out16 = (unsigned short*)outp;
        #pragma unroll 1
        for (int m = 0; m < 8; ++m) {
            #pragma unroll
            for (int n = 0; n < 4; ++n) {
                const int col = colbase + n * 16 + cc;
                const float bv = bias[col];
                const bool sc = col < scaleN;
                #pragma unroll
                for (int r = 0; r < 4; ++r) {
                    float v = acc[m][n][r] + bv;
                    if (sc) v *= scale;
                    eb[(cr + r) * 64 + n * 16 + cc] = f2bf(v);
                }
            }
            const int rowg = bm + wm * 128 + m * 16;
            // tile is contiguous 2KB; lane l reads byte l*16 (stride-1, conflict-free)
            u16x8 v0 = *(const u16x8*)(eb + l * 8);
            u16x8 v1 = *(const u16x8*)(eb + 512 + l * 8);
            *(u16x8*)(out16 + (size_t)(rowg + (l >> 3)) * N + colbase + (l & 7) * 8) = v0;
            *(u16x8*)(out16 + (size_t)(rowg + 8 + (l >> 3)) * N + colbase + (l & 7) * 8) = v1;
        }
    } else {
        float* ebf = (float*)(void*)lds + w * 1024;     // 4 KiB per wave
        float* outf = (float*)outp;
        #pragma unroll 1
        for (int m = 0; m < 8; ++m) {
            #pragma unroll
            for (int n = 0; n < 4; ++n) {
                const float bv = bias[colbase + n * 16 + cc];
                #pragma unroll
                for (int r = 0; r < 4; ++r)
                    ebf[(cr + r) * 64 + n * 16 + cc] = acc[m][n][r] + bv;
            }
            const int rowg = bm + wm * 128 + m * 16;
            #pragma unroll
            for (int s = 0; s < 4; ++s) {
                f32x4 v = *(const f32x4*)(ebf + s * 256 + l * 4);   // stride-1
                *(f32x4*)(outf + (size_t)(rowg + s * 4 + (l >> 4)) * N + colbase + (l & 15) * 4) = v;
            }
        }
    }
}

// ---------------- MFMA neighborhood attention (verified round 4) ----------------
__global__ __launch_bounds__(256)
void natten_kernel(const unsigned short* __restrict__ qkv, unsigned short* __restrict__ attn_bf)
{
    __shared__ unsigned short smem[4 * 5888];   // per wave: K 32x72 + V^T 64x56
    const int t = threadIdx.x;
    const int w = t >> 6, l = t & 63;
    const int c15 = l & 15, g = l >> 4;
    const int blk = blockIdx.x;
    const int tg = blk & 15;
    const int h = (blk >> 4) % NHEADS;
    const int b = blk / (16 * NHEADS);
    const int ti = (tg >> 2) * 16, tj = (tg & 3) * 16;
    const int pi0 = ti + w * 4;
    const int ws = min(max(pi0 - 3, 0), IMG_H - 10);
    const int cs = min(max(tj - 3, 0), IMG_W - 22);
    const int pixbase = b * 4096;

    unsigned short* Kl = smem + w * 5888;
    unsigned short* Vt = Kl + 2304;

    const int pj = tj + c15;
    const int sj = min(max(pj - 3, 0), IMG_W - KSZ);
    const unsigned int cm = 0x7Fu << (sj - cs);
    unsigned int rm[4];
    #pragma unroll
    for (int qt = 0; qt < 4; ++qt) {
        int si = min(max(pi0 + qt - 3, 0), IMG_H - KSZ);
        rm[qt] = 0x7Fu << (si - ws);
    }

    bf16x8 qf[4][2];
    #pragma unroll
    for (int qt = 0; qt < 4; ++qt)
        #pragma unroll
        for (int dh = 0; dh < 2; ++dh)
            qf[qt][dh] = *(const bf16x8*)(qkv +
                (size_t)(pixbase + (pi0 + qt) * 64 + tj + c15) * QKV_N + h * HDIM + dh * 32 + g * 8);

    const int sr = l & 31;
    const int h5 = l >> 5;
    const int sig = ((sr & 12) << 1) | ((sr & 16) >> 2) | (sr & 3);  // slot perm 8g+4t+j

    u16x8 kst[4], vst[4];

    {
        int ur = sr / 22, uc = sr - ur * 22;
        int prow = min(ws + ur, IMG_H - 1);
        const u16x8* gk = (const u16x8*)(qkv +
            (size_t)(pixbase + prow * 64 + cs + uc) * QKV_N + EMBED + h * HDIM + h5 * 32);
        #pragma unroll
        for (int i = 0; i < 4; ++i) { kst[i] = gk[i]; vst[i] = gk[i + 96]; }
    }
    #pragma unroll
    for (int i = 0; i < 4; ++i) *(u16x8*)(Kl + sr * 72 + h5 * 32 + i * 8) = kst[i];
    #pragma unroll
    for (int i = 0; i < 4; ++i)
        #pragma unroll
        for (int e = 0; e < 8; ++e)
            Vt[(h5 * 32 + i * 8 + e) * 56 + sig] = vst[i][e];

    f32x4 oacc[4][4] = {};
    float spart[4] = {0.f, 0.f, 0.f, 0.f};

    #pragma unroll 1
    for (int C = 0; C < 7; ++C) {
        if (C < 6) {
            int kk = (C + 1) * 32 + sr;
            int ur = kk / 22, uc = kk - ur * 22;
            int prow = min(ws + ur, IMG_H - 1);
            const u16x8* gk = (const u16x8*)(qkv +
                (size_t)(pixbase + prow * 64 + cs + uc) * QKV_N + EMBED + h * HDIM + h5 * 32);
            #pragma unroll
            for (int i = 0; i < 4; ++i) { kst[i] = gk[i]; vst[i] = gk[i + 96]; }
        }

        bf16x8 ka[2][2], vb[4];
        #pragma unroll
        for (int kt = 0; kt < 2; ++kt)
            #pragma unroll
            for (int dh = 0; dh < 2; ++dh)
                ka[kt][dh] = *(const bf16x8*)(Kl + (kt * 16 + c15) * 72 + dh * 32 + g * 8);
        #pragma unroll
        for (int dt = 0; dt < 4; ++dt)
            vb[dt] = *(const bf16x8*)(Vt + (dt * 16 + c15) * 56 + g * 8);

        int kk0 = C * 32 + 4 * g;
        int a22 = kk0 / 22;
        int uc0 = kk0 - a22 * 22;
        int urx[2][4]; unsigned int cb[2][4];
        #pragma unroll
        for (int kt = 0; kt < 2; ++kt)
            #pragma unroll
            for (int r = 0; r < 4; ++r) {
                int x = uc0 + kt * 16 + r;
                int wrp = x >= 22;
                int uc = x - (wrp ? 22 : 0);
                urx[kt][r] = a22 + wrp;
                cb[kt][r] = (cm >> uc) & 1u;
            }

        #pragma unroll
        for (int qt = 0; qt < 4; ++qt) {
            f32x4 s0 = {}, s1 = {};
            s0 = __builtin_amdgcn_mfma_f32_16x16x32_bf16(ka[0][0], qf[qt][0], s0, 0, 0, 0);
            s0 = __builtin_amdgcn_mfma_f32_16x16x32_bf16(ka[0][1], qf[qt][1], s0, 0, 0, 0);
            s1 = __builtin_amdgcn_mfma_f32_16x16x32_bf16(ka[1][0], qf[qt][0], s1, 0, 0, 0);
            s1 = __builtin_amdgcn_mfma_f32_16x16x32_bf16(ka[1][1], qf[qt][1], s1, 0, 0, 0);
            float p[2][4];
            #pragma unroll
            for (int r = 0; r < 4; ++r) {
                float e0 = exp2f(s0[r]);
                float e1 = exp2f(s1[r]);
                p[0][r] = ((rm[qt] >> urx[0][r]) & cb[0][r]) ? e0 : 0.f;
                p[1][r] = ((rm[qt] >> urx[1][r]) & cb[1][r]) ? e1 : 0.f;
                spart[qt] += p[0][r] + p[1][r];
            }
            unsigned int pk[4];
            asm("v_cvt_pk_bf16_f32 %0, %1, %2" : "=v"(pk[0]) : "v"(p[0][0]), "v"(p[0][1]));
            asm("v_cvt_pk_bf16_f32 %0, %1, %2" : "=v"(pk[1]) : "v"(p[0][2]), "v"(p[0][3]));
            asm("v_cvt_pk_bf16_f32 %0, %1, %2" : "=v"(pk[2]) : "v"(p[1][0]), "v"(p[1][1]));
            asm("v_cvt_pk_bf16_f32 %0, %1, %2" : "=v"(pk[3]) : "v"(p[1][2]), "v"(p[1][3]));
            bf16x8 pa = *(bf16x8*)pk;
            #pragma unroll
            for (int dt = 0; dt < 4; ++dt)
                oacc[qt][dt] = __builtin_amdgcn_mfma_f32_16x16x32_bf16(pa, vb[dt], oacc[qt][dt], 0, 0, 0);
        }

        if (C < 6) {
            #pragma unroll
            for (int i = 0; i < 4; ++i) *(u16x8*)(Kl + sr * 72 + h5 * 32 + i * 8) = kst[i];
            #pragma unroll
            for (int i = 0; i < 4; ++i)
                #pragma unroll
                for (int e = 0; e < 8; ++e)
                    Vt[(h5 * 32 + i * 8 + e) * 56 + sig] = vst[i][e];
        }
    }

    #pragma unroll
    for (int qt = 0; qt < 4; ++qt) {
        float s = spart[qt];
        s += __shfl_xor(s, 16);
        s += __shfl_xor(s, 32);
        #pragma unroll
        for (int r = 0; r < 4; ++r) {
            float sb = __shfl(s, 4 * g + r);
            float inv = __builtin_amdgcn_rcpf(sb);
            size_t obase = (size_t)(pixbase + (pi0 + qt) * 64 + tj + 4 * g + r) * EMBED
                         + h * HDIM + c15;
            #pragma unroll
            for (int dt = 0; dt < 4; ++dt)
                attn_bf[obase + dt * 16] = f2bf(oacc[qt][dt][r] * inv);
        }
    }
}

// ---------------- launch ----------------
extern "C" void kernel_launch(void* const* d_in, const int* in_sizes, int n_in,
                              void* d_out, int out_size, void* d_ws, size_t ws_size,
                              hipStream_t stream)
{
    const float* x      = (const float*)d_in[0];
    const float* w_qkv  = (const float*)d_in[1];
    const float* b_qkv  = (const float*)d_in[2];
    const float* w_proj = (const float*)d_in[3];
    const float* b_proj = (const float*)d_in[4];
    float* out = (float*)d_out;

    // workspace (~206 MB)
    char* p = (char*)d_ws;
    unsigned short* qkv = (unsigned short*)p;     p += (size_t)NTOK * QKV_N * 2;       // 151 MB
    unsigned short* xbf = (unsigned short*)p;     // aliased: x_bf then attn_bf
    unsigned short* attn_bf = xbf;                p += (size_t)NTOK * EMBED * 2;       // 50 MB
    unsigned short* wq_bf = (unsigned short*)p;   p += (size_t)QKV_N * EMBED * 2;      // 3.5 MB
    unsigned short* wp_bf = (unsigned short*)p;

    const float scale = 0.125f * 1.44269504088896f;  // HDIM^-0.5 * log2(e)

    {
        // fused conversion: (NX + NQ + NP) float4 elements = 6881280 -> 26880 blocks
        const int ntot = (NTOK * EMBED + QKV_N * EMBED + EMBED * EMBED) / 4;
        cvt_all_kernel<<<(ntot + 255) / 256, 256, 0, stream>>>(
            x, w_qkv, w_proj, xbf, wq_bf, wp_bf);
    }

    {
        // GEMM1: M=32768, N=2304 -> 1152 blocks; per XCD: 16 bm-groups x 9 bn (serpentine)
        gemm256<1><<<(NTOK / 256) * (QKV_N / 256), 512, 0, stream>>>(
            xbf, wq_bf, b_qkv, qkv, NTOK, QKV_N, EMBED, EMBED, scale);
    }

    natten_kernel<<<BATCH * NHEADS * 16, 256, 0, stream>>>(qkv, attn_bf);

    {
        // GEMM2: M=32768, N=768 -> 384 blocks; per XCD: 16 bm-groups x 3 bn (serpentine)
        gemm256<0><<<(NTOK / 256) * (EMBED / 256), 512, 0, stream>>>(
            attn_bf, wp_bf, b_proj, out, NTOK, EMBED, EMBED, 0, 1.0f);
    }
}

// Round 12
// 314.957 us; speedup vs baseline: 1.6119x; 1.6119x over previous
//
#include <hip/hip_runtime.h>
#include <cstddef>

#define EMBED   768
#define NHEADS  12
#define HDIM    64
#define KSZ     7
#define IMG_H   64
#define IMG_W   64
#define BATCH   8
#define NTOK    (BATCH*IMG_H*IMG_W)   /* 32768 */
#define QKV_N   (3*EMBED)             /* 2304  */

typedef __attribute__((ext_vector_type(8))) short  bf16x8;
typedef __attribute__((ext_vector_type(4))) float  f32x4;
typedef __attribute__((ext_vector_type(8))) unsigned short u16x8;
typedef __attribute__((ext_vector_type(4))) unsigned short u16x4;

__device__ __forceinline__ unsigned short f2bf(float f) {
    unsigned int u = __float_as_uint(f);
    u += 0x7FFFu + ((u >> 16) & 1u);      // RNE
    return (unsigned short)(u >> 16);
}

__device__ __forceinline__ void gload_lds16(const void* g, void* l) {
    __builtin_amdgcn_global_load_lds(
        (const __attribute__((address_space(1))) unsigned int*)g,
        (__attribute__((address_space(3))) unsigned int*)l, 16, 0, 0);
}

// ---------------- fused fp32 -> bf16 conversion ----------------
__global__ __launch_bounds__(256)
void cvt_all_kernel(const float* __restrict__ x, const float* __restrict__ wq,
                    const float* __restrict__ wp, unsigned short* __restrict__ xbf,
                    unsigned short* __restrict__ wqbf, unsigned short* __restrict__ wpbf)
{
    const int NX = NTOK * EMBED / 4;
    const int NQ = QKV_N * EMBED / 4;
    const int NP = EMBED * EMBED / 4;
    int i = blockIdx.x * 256 + threadIdx.x;
    const float* src; unsigned short* dst; int j;
    if (i < NX)           { src = x;  dst = xbf;  j = i; }
    else if (i < NX + NQ) { src = wq; dst = wqbf; j = i - NX; }
    else if (i < NX + NQ + NP) { src = wp; dst = wpbf; j = i - NX - NQ; }
    else return;
    float4 f = *(const float4*)(src + (size_t)j * 4);
    u16x4 o;
    o[0] = f2bf(f.x); o[1] = f2bf(f.y); o[2] = f2bf(f.z); o[3] = f2bf(f.w);
    *(u16x4*)(dst + (size_t)j * 4) = o;
}

// ---------------- bf16 MFMA GEMM v9: 256x256, BK=32, 4 buffers, prefetch depth 3 ----
// Changes vs round-10 v7 (proven 136us, FETCH 100MB, 0 conflicts):
//   BK 64->32, LDS 2x64KB -> 4x32KB, 2 phases/tile, all 4 stage-loads in phase 1,
//   counted vmcnt(8) (12 loads in flight = tiles t+1..t+3). Issue->wait distance
//   ~4 phases (~400cy, covers L2 latency) vs ~2 phases before.
// Race audit (round-9 2-barrier standard): buf(t%4) last read at phase1(t); its reader
// drains lgkm via MFMA BEFORE barrier end-ph0(t+1); overwrite (stage t+4) issues after
// that barrier -> >= 2-barrier separation. Per-acc K-order unchanged -> bit-identical.
// Epilogue: SCALAR stores (empirical law, measured r7+r11: multi-row 16B vector stores
// amplify WRITE_SIZE 5x; scalar 2B stores write-combine to exactly 1x).
template<int BF16OUT>
__global__ __launch_bounds__(512)
void gemm256(const unsigned short* __restrict__ A, const unsigned short* __restrict__ W,
             const float* __restrict__ bias, void* __restrict__ outp,
             int M, int N, int K, int scaleN, float scale)
{
    __shared__ unsigned short lds[65536];   // 128 KiB = 4 bufs x 16384 ushorts (A 8K, B 8K)
    const int t_ = threadIdx.x;
    const int l = t_ & 63, w = t_ >> 6;
    const int wm = w >> 2, wn = w & 3;

    // bn-fastest serpentine mapping within XCD (proven: FETCH 229->100 MB)
    const int nby = N >> 8;
    const int xcd = blockIdx.x & 7;
    const int loc = blockIdx.x >> 3;
    const int bmg = loc / nby;
    int bnq = loc - bmg * nby;
    if (bmg & 1) bnq = nby - 1 - bnq;
    const int bm = (xcd * (((M >> 8) >> 3)) + bmg) << 8;
    const int bn = bnq << 8;

    // staging source (quad-coalesced, slot-permuted; proven layout)
    const int kperm8 = ((l & 3) ^ ((l >> 3) & 3)) * 8;
    const unsigned short* gA = A + (size_t)(bm + w * 16 + (l >> 2)) * K + kperm8;
    const unsigned short* gB = W + (size_t)(bn + w * 16 + (l >> 2)) * K + kperm8;
    const size_t rstep = (size_t)128 * K;          // +8 subtiles (128 rows)

    const int foff = (l & 15) * 32 + (((l >> 4) ^ ((l >> 1) & 3)) * 8);
    const int aoff = wm * 8 * 512;                 // A subtile (wm*8 + m)
    const int boff = 8192 + wn * 4 * 512;          // B subtile (wn*4 + n)

    f32x4 acc[8][4] = {};
    const int NT = K / 32;                         // 24

#define BARRIER() asm volatile("s_barrier" ::: "memory")
#define WAITV8()  asm volatile("s_waitcnt vmcnt(8)" ::: "memory")
#define WAITV4()  asm volatile("s_waitcnt vmcnt(4)" ::: "memory")
#define WAITV0()  asm volatile("s_waitcnt vmcnt(0)" ::: "memory")
    // stage tile tt into buffer (tt&3): 4 loads/thread, FIFO group of 4
#define STG(tt) do { \
        const int cc_ = ((tt) & 3) * 16384; const size_t ko_ = (size_t)(tt) * 32; \
        gload_lds16(gA + ko_,         lds + cc_ + w * 512); \
        gload_lds16(gA + rstep + ko_, lds + cc_ + (w + 8) * 512); \
        gload_lds16(gB + ko_,         lds + cc_ + 8192 + w * 512); \
        gload_lds16(gB + rstep + ko_, lds + cc_ + 8192 + (w + 8) * 512); } while (0)

    // prologue: stage tiles 0,1,2 (12 loads); retire tile 0
    STG(0); STG(1); STG(2);
    WAITV8();
    BARRIER();

    for (int t = 0; t < NT; ++t) {
        const int c = (t & 3) * 16384;
        bf16x8 a[4], bq[4];

        // ---- phase 0: m0-3 x n0-3 (8 ds_read) ----
        #pragma unroll
        for (int m = 0; m < 4; ++m) a[m]  = *(const bf16x8*)(lds + c + aoff + m * 512 + foff);
        #pragma unroll
        for (int n = 0; n < 4; ++n) bq[n] = *(const bf16x8*)(lds + c + boff + n * 512 + foff);
        BARRIER();
        __builtin_amdgcn_s_setprio(1);
        #pragma unroll
        for (int m = 0; m < 4; ++m)
            #pragma unroll
            for (int n = 0; n < 4; ++n)
                acc[m][n] = __builtin_amdgcn_mfma_f32_16x16x32_bf16(a[m], bq[n], acc[m][n], 0, 0, 0);
        __builtin_amdgcn_s_setprio(0);

        // ---- phase 1: m4-7 x n0-3 (4 ds_read) + stage tile t+3 + counted wait ----
        #pragma unroll
        for (int m = 0; m < 4; ++m) a[m] = *(const bf16x8*)(lds + c + aoff + (4 + m) * 512 + foff);
        if (t + 3 < NT)      { STG(t + 3); WAITV8(); }
        else if (t == NT - 3)  WAITV4();
        else if (t == NT - 2)  WAITV0();
        BARRIER();
        __builtin_amdgcn_s_setprio(1);
        #pragma unroll
        for (int m = 0; m < 4; ++m)
            #pragma unroll
            for (int n = 0; n < 4; ++n)
                acc[4 + m][n] = __builtin_amdgcn_mfma_f32_16x16x32_bf16(a[m], bq[n], acc[4 + m][n], 0, 0, 0);
        __builtin_amdgcn_s_setprio(0);
    }
#undef BARRIER
#undef WAITV8
#undef WAITV4
#undef WAITV0
#undef STG

    // ---- scalar epilogue (proven WRITE_SIZE == data size) ----
    const int cr = (l >> 4) * 4;
    const int cc = l & 15;
    #pragma unroll
    for (int m = 0; m < 8; ++m) {
        #pragma unroll
        for (int n = 0; n < 4; ++n) {
            const int col = bn + wn * 64 + n * 16 + cc;
            const float bv = bias[col];
            const bool sc = col < scaleN;
            #pragma unroll
            for (int r = 0; r < 4; ++r) {
                const int row = bm + wm * 128 + m * 16 + cr + r;
                float v = acc[m][n][r] + bv;
                if (sc) v *= scale;
                if (BF16OUT) ((unsigned short*)outp)[(size_t)row * N + col] = f2bf(v);
                else         ((float*)outp)[(size_t)row * N + col] = v;
            }
        }
    }
}

// ---------------- MFMA neighborhood attention (verified round 4) ----------------
__global__ __launch_bounds__(256)
void natten_kernel(const unsigned short* __restrict__ qkv, unsigned short* __restrict__ attn_bf)
{
    __shared__ unsigned short smem[4 * 5888];   // per wave: K 32x72 + V^T 64x56
    const int t = threadIdx.x;
    const int w = t >> 6, l = t & 63;
    const int c15 = l & 15, g = l >> 4;
    const int blk = blockIdx.x;
    const int tg = blk & 15;
    const int h = (blk >> 4) % NHEADS;
    const int b = blk / (16 * NHEADS);
    const int ti = (tg >> 2) * 16, tj = (tg & 3) * 16;
    const int pi0 = ti + w * 4;
    const int ws = min(max(pi0 - 3, 0), IMG_H - 10);
    const int cs = min(max(tj - 3, 0), IMG_W - 22);
    const int pixbase = b * 4096;

    unsigned short* Kl = smem + w * 5888;
    unsigned short* Vt = Kl + 2304;

    const int pj = tj + c15;
    const int sj = min(max(pj - 3, 0), IMG_W - KSZ);
    const unsigned int cm = 0x7Fu << (sj - cs);
    unsigned int rm[4];
    #pragma unroll
    for (int qt = 0; qt < 4; ++qt) {
        int si = min(max(pi0 + qt - 3, 0), IMG_H - KSZ);
        rm[qt] = 0x7Fu << (si - ws);
    }

    bf16x8 qf[4][2];
    #pragma unroll
    for (int qt = 0; qt < 4; ++qt)
        #pragma unroll
        for (int dh = 0; dh < 2; ++dh)
            qf[qt][dh] = *(const bf16x8*)(qkv +
                (size_t)(pixbase + (pi0 + qt) * 64 + tj + c15) * QKV_N + h * HDIM + dh * 32 + g * 8);

    const int sr = l & 31;
    const int h5 = l >> 5;
    const int sig = ((sr & 12) << 1) | ((sr & 16) >> 2) | (sr & 3);  // slot perm 8g+4t+j

    u16x8 kst[4], vst[4];

    {
        int ur = sr / 22, uc = sr - ur * 22;
        int prow = min(ws + ur, IMG_H - 1);
        const u16x8* gk = (const u16x8*)(qkv +
            (size_t)(pixbase + prow * 64 + cs + uc) * QKV_N + EMBED + h * HDIM + h5 * 32);
        #pragma unroll
        for (int i = 0; i < 4; ++i) { kst[i] = gk[i]; vst[i] = gk[i + 96]; }
    }
    #pragma unroll
    for (int i = 0; i < 4; ++i) *(u16x8*)(Kl + sr * 72 + h5 * 32 + i * 8) = kst[i];
    #pragma unroll
    for (int i = 0; i < 4; ++i)
        #pragma unroll
        for (int e = 0; e < 8; ++e)
            Vt[(h5 * 32 + i * 8 + e) * 56 + sig] = vst[i][e];

    f32x4 oacc[4][4] = {};
    float spart[4] = {0.f, 0.f, 0.f, 0.f};

    #pragma unroll 1
    for (int C = 0; C < 7; ++C) {
        if (C < 6) {
            int kk = (C + 1) * 32 + sr;
            int ur = kk / 22, uc = kk - ur * 22;
            int prow = min(ws + ur, IMG_H - 1);
            const u16x8* gk = (const u16x8*)(qkv +
                (size_t)(pixbase + prow * 64 + cs + uc) * QKV_N + EMBED + h * HDIM + h5 * 32);
            #pragma unroll
            for (int i = 0; i < 4; ++i) { kst[i] = gk[i]; vst[i] = gk[i + 96]; }
        }

        bf16x8 ka[2][2], vb[4];
        #pragma unroll
        for (int kt = 0; kt < 2; ++kt)
            #pragma unroll
            for (int dh = 0; dh < 2; ++dh)
                ka[kt][dh] = *(const bf16x8*)(Kl + (kt * 16 + c15) * 72 + dh * 32 + g * 8);
        #pragma unroll
        for (int dt = 0; dt < 4; ++dt)
            vb[dt] = *(const bf16x8*)(Vt + (dt * 16 + c15) * 56 + g * 8);

        int kk0 = C * 32 + 4 * g;
        int a22 = kk0 / 22;
        int uc0 = kk0 - a22 * 22;
        int urx[2][4]; unsigned int cb[2][4];
        #pragma unroll
        for (int kt = 0; kt < 2; ++kt)
            #pragma unroll
            for (int r = 0; r < 4; ++r) {
                int x = uc0 + kt * 16 + r;
                int wrp = x >= 22;
                int uc = x - (wrp ? 22 : 0);
                urx[kt][r] = a22 + wrp;
                cb[kt][r] = (cm >> uc) & 1u;
            }

        #pragma unroll
        for (int qt = 0; qt < 4; ++qt) {
            f32x4 s0 = {}, s1 = {};
            s0 = __builtin_amdgcn_mfma_f32_16x16x32_bf16(ka[0][0], qf[qt][0], s0, 0, 0, 0);
            s0 = __builtin_amdgcn_mfma_f32_16x16x32_bf16(ka[0][1], qf[qt][1], s0, 0, 0, 0);
            s1 = __builtin_amdgcn_mfma_f32_16x16x32_bf16(ka[1][0], qf[qt][0], s1, 0, 0, 0);
            s1 = __builtin_amdgcn_mfma_f32_16x16x32_bf16(ka[1][1], qf[qt][1], s1, 0, 0, 0);
            float p[2][4];
            #pragma unroll
            for (int r = 0; r < 4; ++r) {
                float e0 = exp2f(s0[r]);
                float e1 = exp2f(s1[r]);
                p[0][r] = ((rm[qt] >> urx[0][r]) & cb[0][r]) ? e0 : 0.f;
                p[1][r] = ((rm[qt] >> urx[1][r]) & cb[1][r]) ? e1 : 0.f;
                spart[qt] += p[0][r] + p[1][r];
            }
            unsigned int pk[4];
            asm("v_cvt_pk_bf16_f32 %0, %1, %2" : "=v"(pk[0]) : "v"(p[0][0]), "v"(p[0][1]));
            asm("v_cvt_pk_bf16_f32 %0, %1, %2" : "=v"(pk[1]) : "v"(p[0][2]), "v"(p[0][3]));
            asm("v_cvt_pk_bf16_f32 %0, %1, %2" : "=v"(pk[2]) : "v"(p[1][0]), "v"(p[1][1]));
            asm("v_cvt_pk_bf16_f32 %0, %1, %2" : "=v"(pk[3]) : "v"(p[1][2]), "v"(p[1][3]));
            bf16x8 pa = *(bf16x8*)pk;
            #pragma unroll
            for (int dt = 0; dt < 4; ++dt)
                oacc[qt][dt] = __builtin_amdgcn_mfma_f32_16x16x32_bf16(pa, vb[dt], oacc[qt][dt], 0, 0, 0);
        }

        if (C < 6) {
            #pragma unroll
            for (int i = 0; i < 4; ++i) *(u16x8*)(Kl + sr * 72 + h5 * 32 + i * 8) = kst[i];
            #pragma unroll
            for (int i = 0; i < 4; ++i)
                #pragma unroll
                for (int e = 0; e < 8; ++e)
                    Vt[(h5 * 32 + i * 8 + e) * 56 + sig] = vst[i][e];
        }
    }

    #pragma unroll
    for (int qt = 0; qt < 4; ++qt) {
        float s = spart[qt];
        s += __shfl_xor(s, 16);
        s += __shfl_xor(s, 32);
        #pragma unroll
        for (int r = 0; r < 4; ++r) {
            float sb = __shfl(s, 4 * g + r);
            float inv = __builtin_amdgcn_rcpf(sb);
            size_t obase = (size_t)(pixbase + (pi0 + qt) * 64 + tj + 4 * g + r) * EMBED
                         + h * HDIM + c15;
            #pragma unroll
            for (int dt = 0; dt < 4; ++dt)
                attn_bf[obase + dt * 16] = f2bf(oacc[qt][dt][r] * inv);
        }
    }
}

// ---------------- launch ----------------
extern "C" void kernel_launch(void* const* d_in, const int* in_sizes, int n_in,
                              void* d_out, int out_size, void* d_ws, size_t ws_size,
                              hipStream_t stream)
{
    const float* x      = (const float*)d_in[0];
    const float* w_qkv  = (const float*)d_in[1];
    const float* b_qkv  = (const float*)d_in[2];
    const float* w_proj = (const float*)d_in[3];
    const float* b_proj = (const float*)d_in[4];
    float* out = (float*)d_out;

    // workspace (~206 MB)
    char* p = (char*)d_ws;
    unsigned short* qkv = (unsigned short*)p;     p += (size_t)NTOK * QKV_N * 2;       // 151 MB
    unsigned short* xbf = (unsigned short*)p;     // aliased: x_bf then attn_bf
    unsigned short* attn_bf = xbf;                p += (size_t)NTOK * EMBED * 2;       // 50 MB
    unsigned short* wq_bf = (unsigned short*)p;   p += (size_t)QKV_N * EMBED * 2;      // 3.5 MB
    unsigned short* wp_bf = (unsigned short*)p;

    const float scale = 0.125f * 1.44269504088896f;  // HDIM^-0.5 * log2(e)

    {
        const int ntot = (NTOK * EMBED + QKV_N * EMBED + EMBED * EMBED) / 4;
        cvt_all_kernel<<<(ntot + 255) / 256, 256, 0, stream>>>(
            x, w_qkv, w_proj, xbf, wq_bf, wp_bf);
    }

    {
        // GEMM1: M=32768, N=2304 -> 1152 blocks; per XCD: 16 bm-groups x 9 bn (serpentine)
        gemm256<1><<<(NTOK / 256) * (QKV_N / 256), 512, 0, stream>>>(
            xbf, wq_bf, b_qkv, qkv, NTOK, QKV_N, EMBED, EMBED, scale);
    }

    natten_kernel<<<BATCH * NHEADS * 16, 256, 0, stream>>>(qkv, attn_bf);

    {
        // GEMM2: M=32768, N=768 -> 384 blocks; per XCD: 16 bm-groups x 3 bn (serpentine)
        gemm256<0><<<(NTOK / 256) * (EMBED / 256), 512, 0, stream>>>(
            attn_bf, wp_bf, b_proj, out, NTOK, EMBED, EMBED, 0, 1.0f);
    }
}